// Round 8
// baseline (168.398 us; speedup 1.0000x reference)
//
#include <hip/hip_runtime.h>

typedef short short8 __attribute__((ext_vector_type(8)));
typedef float f32x4 __attribute__((ext_vector_type(4)));
typedef float f32x16 __attribute__((ext_vector_type(16)));

#define QSCALE 0.18033688011112042f  // 0.125 * log2(e), folded into Wq/bq

__device__ __forceinline__ unsigned short f2bf(float f) {
  unsigned u = __builtin_bit_cast(unsigned, f);
  u += 0x7fffu + ((u >> 16) & 1u);
  return (unsigned short)(u >> 16);
}

__device__ __forceinline__ void gload16(const void* g, void* l) {
  typedef __attribute__((address_space(1))) unsigned int gas;
  typedef __attribute__((address_space(3))) unsigned int las;
  __builtin_amdgcn_global_load_lds((gas*)(unsigned long long)g,
                                   (las*)(unsigned)(unsigned long long)l, 16, 0, 0);
}

__device__ __forceinline__ short8 mk8(unsigned r0, unsigned r1, unsigned r2, unsigned r3) {
  union { unsigned u[4]; short8 s; } t;
  t.u[0] = r0; t.u[1] = r1; t.u[2] = r2; t.u[3] = r3;
  return t.s;
}

#define MFMA16(a, b, c) __builtin_amdgcn_mfma_f32_16x16x32_bf16(a, b, c, 0, 0, 0)
#define MFMA32(a, b, c) __builtin_amdgcn_mfma_f32_32x32x16_bf16(a, b, c, 0, 0, 0)

// ---------------------------------------------------------------- weights ----
// W fp32 [k][n] -> Wt bf16 [n][k]; Wq additionally pre-scaled by QSCALE.
__global__ __launch_bounds__(256) void wtrans_kernel(
    const float* __restrict__ Wq, const float* __restrict__ Wk,
    const float* __restrict__ Wv, const float* __restrict__ Wo,
    unsigned short* __restrict__ Wt) {
  const int wsel = blockIdx.z;
  const float* W = wsel == 0 ? Wq : wsel == 1 ? Wk : wsel == 2 ? Wv : Wo;
  const float wscale = (wsel == 0) ? QSCALE : 1.0f;
  unsigned short* out = Wt + (long)wsel * 1048576;
  __shared__ float lds[64][65];
  const int t = threadIdx.x;
  const int k0 = blockIdx.x * 64, n0 = blockIdx.y * 64;
#pragma unroll
  for (int i = 0; i < 4; ++i) {
    int r = (t >> 4) + i * 16, c4 = (t & 15) * 4;
    float4 vv = *(const float4*)(W + (long)(k0 + r) * 1024 + n0 + c4);
    lds[r][c4] = vv.x; lds[r][c4 + 1] = vv.y; lds[r][c4 + 2] = vv.z; lds[r][c4 + 3] = vv.w;
  }
  __syncthreads();
#pragma unroll
  for (int i = 0; i < 16; ++i) {
    int flat = t + i * 256;
    int n = flat >> 6, kk = flat & 63;
    out[(long)(n0 + n) * 1024 + k0 + kk] = f2bf(lds[kk][n] * wscale);
  }
}

// ---------------------------------------------------------------- mask pack --
__global__ __launch_bounds__(256) void maskpack_kernel(const int* __restrict__ mask,
                                                       unsigned* __restrict__ bits) {
  const long n = 8388608;  // 2*2048*2048
  const long stride = (long)gridDim.x * 256;
  const int lane = threadIdx.x & 63;
  for (long i = (long)blockIdx.x * 256 + threadIdx.x; i < n; i += stride) {
    unsigned long long bal = __ballot(mask[i] != 0);
    if ((lane & 31) == 0) bits[i >> 5] = (unsigned)(bal >> (lane & 32));
  }
}

// ---------------------------------------------------------------- layernorm --
__global__ __launch_bounds__(256) void ln_kernel(
    const float* __restrict__ q, const float* __restrict__ k, const float* __restrict__ v,
    const float* __restrict__ gamma, const float* __restrict__ beta,
    unsigned short* __restrict__ lnq, unsigned short* __restrict__ lnk,
    unsigned short* __restrict__ lnv) {
  const int row = blockIdx.x, which = blockIdx.y;
  const float* x = (which == 0 ? q : which == 1 ? k : v) + (long)row * 1024;
  unsigned short* y = (which == 0 ? lnq : which == 1 ? lnk : lnv) + (long)row * 1024;
  const int t = threadIdx.x, lane = t & 63, wv = t >> 6;
  float4 xv = ((const float4*)x)[t];
  float s = xv.x + xv.y + xv.z + xv.w;
  float s2 = xv.x * xv.x + xv.y * xv.y + xv.z * xv.z + xv.w * xv.w;
#pragma unroll
  for (int off = 32; off > 0; off >>= 1) {
    s += __shfl_down(s, off);
    s2 += __shfl_down(s2, off);
  }
  __shared__ float red[8];
  if (lane == 0) { red[wv] = s; red[wv + 4] = s2; }
  __syncthreads();
  float tot = red[0] + red[1] + red[2] + red[3];
  float tot2 = red[4] + red[5] + red[6] + red[7];
  float mu = tot * (1.0f / 1024.0f);
  float var = tot2 * (1.0f / 1024.0f) - mu * mu;
  float rs = rsqrtf(var + 1e-5f);
  float4 g = ((const float4*)gamma)[t];
  float4 be = ((const float4*)beta)[t];
  ushort4 o;
  o.x = f2bf((xv.x - mu) * rs * g.x + be.x);
  o.y = f2bf((xv.y - mu) * rs * g.y + be.y);
  o.z = f2bf((xv.z - mu) * rs * g.z + be.z);
  o.w = f2bf((xv.w - mu) * rs * g.w + be.w);
  ((ushort4*)y)[t] = o;
}

// ---------------------------------------------------------------- GEMM -------
// MODE 0: bf16 out, heads layout [B,H,S,64]; z==2 writes V^T [BH][64][S] to outV.
// MODE 1: fp32 out row-major.
template <int BM, int MODE>
__global__ __launch_bounds__(256) void gemm_kernel(
    const unsigned short* __restrict__ A0, const unsigned short* __restrict__ A1,
    const unsigned short* __restrict__ A2, const unsigned short* __restrict__ Wt,
    const float* __restrict__ b0, const float* __restrict__ b1,
    const float* __restrict__ b2, unsigned short* __restrict__ outB,
    unsigned short* __restrict__ outV, float* __restrict__ outF) {
  constexpr int BK = 64;
  constexpr int MI = BM / 32;
  const int z = blockIdx.z;
  const unsigned short* A = z == 0 ? A0 : z == 1 ? A1 : A2;
  const unsigned short* Bt = Wt + (long)z * 1048576;
  const float* bias = z == 0 ? b0 : z == 1 ? b1 : b2;
  unsigned short* outz = outB + (long)z * 4194304;
  const float bscale = (MODE == 0 && z == 0) ? QSCALE : 1.0f;

  __shared__ char lds[BM * 128 + 16384];
  char* As = lds;
  char* Bs = lds + BM * 128;
  const int tid = threadIdx.x, lane = tid & 63, w = tid >> 6;
  const int wr = w >> 1, wc = w & 1;
  const int m0 = blockIdx.x * BM, n0 = blockIdx.y * 128;
  constexpr int K = 1024;
  constexpr int ACH = BM * 8 / 256;

  f32x4 acc[MI][4] = {};
  for (int kt = 0; kt < K / BK; ++kt) {
    __syncthreads();
#pragma unroll
    for (int i = 0; i < ACH; ++i) {
      int c = tid + i * 256;
      int row = c >> 3, pg = (c & 7) ^ (row & 7);
      gload16(A + (long)(m0 + row) * K + kt * BK + pg * 8, As + c * 16);
    }
#pragma unroll
    for (int i = 0; i < 4; ++i) {
      int c = tid + i * 256;
      int row = c >> 3, pg = (c & 7) ^ (row & 7);
      gload16(Bt + (long)(n0 + row) * K + kt * BK + pg * 8, Bs + c * 16);
    }
    asm volatile("s_waitcnt vmcnt(0)" ::: "memory");
    __syncthreads();
#pragma unroll
    for (int ks = 0; ks < 2; ++ks) {
      short8 af[MI], bf[4];
#pragma unroll
      for (int mi = 0; mi < MI; ++mi) {
        int row = wr * (BM / 2) + mi * 16 + (lane & 15);
        int part = (ks * 4 + (lane >> 4)) ^ (row & 7);
        af[mi] = *(const short8*)(As + row * 128 + part * 16);
      }
#pragma unroll
      for (int ni = 0; ni < 4; ++ni) {
        int row = wc * 64 + ni * 16 + (lane & 15);
        int part = (ks * 4 + (lane >> 4)) ^ (row & 7);
        bf[ni] = *(const short8*)(Bs + row * 128 + part * 16);
      }
#pragma unroll
      for (int mi = 0; mi < MI; ++mi)
#pragma unroll
        for (int ni = 0; ni < 4; ++ni)
          acc[mi][ni] = MFMA16(af[mi], bf[ni], acc[mi][ni]);
    }
  }
#pragma unroll
  for (int mi = 0; mi < MI; ++mi) {
    int mbase = m0 + wr * (BM / 2) + mi * 16 + ((lane >> 4) << 2);
#pragma unroll
    for (int ni = 0; ni < 4; ++ni) {
      int j = n0 + wc * 64 + ni * 16 + (lane & 15);
      float bj = bias[j] * bscale;
      float t0 = acc[mi][ni][0] + bj;
      float t1 = acc[mi][ni][1] + bj;
      float t2 = acc[mi][ni][2] + bj;
      float t3 = acc[mi][ni][3] + bj;
      if constexpr (MODE == 0) {
        int b = mbase >> 11, s = mbase & 2047;
        int h = j >> 6, d = j & 63;
        if (z == 2) {
          unsigned lo, hi;
          asm("v_cvt_pk_bf16_f32 %0, %1, %2" : "=v"(lo) : "v"(t0), "v"(t1));
          asm("v_cvt_pk_bf16_f32 %0, %1, %2" : "=v"(hi) : "v"(t2), "v"(t3));
          uint2 o; o.x = lo; o.y = hi;
          *(uint2*)(outV + ((long)(b * 16 + h) * 64 + d) * 2048 + s) = o;
        } else {
          long base = (((long)(b * 16 + h)) * 2048 + s) * 64 + d;
          outz[base] = f2bf(t0);
          outz[base + 64] = f2bf(t1);
          outz[base + 128] = f2bf(t2);
          outz[base + 192] = f2bf(t3);
        }
      } else {
        outF[(long)mbase * 1024 + j] = t0;
        outF[(long)(mbase + 1) * 1024 + j] = t1;
        outF[(long)(mbase + 2) * 1024 + j] = t2;
        outF[(long)(mbase + 3) * 1024 + j] = t3;
      }
    }
  }
}

// ---------------------------------------------------------------- attention --
// Swapped-QK^T flash attention with 32x32x16 MFMA and fully in-register P
// (cvt_pk_bf16 + v_permlane32_swap_b32 transposes P without LDS). Fixed-max
// softmax (scale pre-folded into Q/Wq). K/V in LDS dbuf (32 KB/block),
// 2-wave blocks of 64 q-rows -> 1024 blocks -> 4 blocks/CU.
// permlane semantics: swap(vdst,vsrc) exchanges vdst.hi <-> vsrc.lo, so
// new_vdst = [vdst.lo|vsrc.lo], new_vsrc = [vdst.hi|vsrc.hi]. PA word0 must be
// [pk(p0,p1)@h0 | pk(p8,p9)@h1]  => vdst = pk(p0,p1), vsrc = pk(p4,p5).
__global__ __launch_bounds__(128, 2) void attn_kernel(
    const unsigned short* __restrict__ qh, const unsigned short* __restrict__ kh,
    const unsigned short* __restrict__ vt, const unsigned* __restrict__ mbits,
    unsigned short* __restrict__ O) {
  constexpr int S = 2048, NT = 32;
  __shared__ char lds[32768];  // K dbuf 2x8K | V dbuf 2x8K
  char* Ks = lds;
  char* Vts = lds + 16384;
  const int tid = threadIdx.x, lane = tid & 63, w = tid >> 6;
  const int qc = lane & 31, h = lane >> 5;

  // XCD-bijective swizzle: 1024 blocks -> 128 consecutive (4 heads) per XCD
  const int flat = blockIdx.y * 32 + blockIdx.x;
  const int fl2 = (flat & 7) * 128 + (flat >> 3);
  const int qb = fl2 & 31, bh = fl2 >> 5, b = bh >> 4;

  const unsigned short* qp = qh + (long)bh * S * 64;
  const unsigned short* kp = kh + (long)bh * S * 64;
  const unsigned short* vp = vt + (long)bh * 64 * S;
  unsigned short* op = O + (long)bh * S * 64;
  const unsigned* mrow = mbits + (long)b * S * 64;
  const int q0 = qb * 64 + w * 32;
  const int myq = q0 + qc;

  // Q as 32x32x16 B-frags: col=q=qc, k(d)= ds4*16 + h*8 + j
  short8 bq_[4];
#pragma unroll
  for (int ds4 = 0; ds4 < 4; ++ds4)
    bq_[ds4] = *(const short8*)(qp + (long)myq * 64 + ds4 * 16 + h * 8);

  f32x16 o_acc[2] = {};
  float lp = 0.f;

#define STAGE(KT, BUF)                                                              \
  {                                                                                 \
    _Pragma("unroll") for (int i = 0; i < 4; ++i) {                                 \
      int cc = tid + i * 128;                                                       \
      int row = cc >> 3, pg = (cc & 7) ^ (row & 7);                                 \
      gload16(kp + (long)((KT)*64 + row) * 64 + pg * 8, Ks + (BUF)*8192 + cc * 16); \
    }                                                                               \
    _Pragma("unroll") for (int i = 0; i < 4; ++i) {                                 \
      int cc = tid + i * 128;                                                       \
      int row = cc >> 3, pg = (cc & 7) ^ (row & 7);                                 \
      gload16(vp + (long)row * S + (KT)*64 + pg * 8, Vts + (BUF)*8192 + cc * 16);   \
    }                                                                               \
  }

  // softmax + P transpose for one 32-kv block: sc f32x16 -> PA0 (k 0..15), PA1 (k 16..31)
#define SM32(SC, MW, PA0, PA1)                                                      \
  {                                                                                 \
    unsigned wsh = (MW) >> (h * 4);                                                 \
    float p[16];                                                                    \
    _Pragma("unroll") for (int r = 0; r < 16; ++r) {                                \
      float e = __builtin_amdgcn_exp2f(SC[r]);                                      \
      int bit = (r & 3) + 8 * (r >> 2);                                             \
      p[r] = ((wsh >> bit) & 1u) ? e : 0.f;                                         \
      lp += p[r];                                                                   \
    }                                                                               \
    unsigned a0, b0, c0, d0, a1, b1, c1, d1;                                        \
    asm("v_cvt_pk_bf16_f32 %0, %1, %2" : "=v"(a0) : "v"(p[0]), "v"(p[1]));          \
    asm("v_cvt_pk_bf16_f32 %0, %1, %2" : "=v"(c0) : "v"(p[2]), "v"(p[3]));          \
    asm("v_cvt_pk_bf16_f32 %0, %1, %2" : "=v"(b0) : "v"(p[4]), "v"(p[5]));          \
    asm("v_cvt_pk_bf16_f32 %0, %1, %2" : "=v"(d0) : "v"(p[6]), "v"(p[7]));          \
    asm("v_cvt_pk_bf16_f32 %0, %1, %2" : "=v"(a1) : "v"(p[8]), "v"(p[9]));          \
    asm("v_cvt_pk_bf16_f32 %0, %1, %2" : "=v"(c1) : "v"(p[10]), "v"(p[11]));        \
    asm("v_cvt_pk_bf16_f32 %0, %1, %2" : "=v"(b1) : "v"(p[12]), "v"(p[13]));        \
    asm("v_cvt_pk_bf16_f32 %0, %1, %2" : "=v"(d1) : "v"(p[14]), "v"(p[15]));        \
    asm("v_permlane32_swap_b32 %0, %1" : "+v"(a0), "+v"(b0));                       \
    asm("v_permlane32_swap_b32 %0, %1" : "+v"(c0), "+v"(d0));                       \
    asm("v_permlane32_swap_b32 %0, %1" : "+v"(a1), "+v"(b1));                       \
    asm("v_permlane32_swap_b32 %0, %1" : "+v"(c1), "+v"(d1));                       \
    PA0 = mk8(a0, c0, b0, d0);                                                      \
    PA1 = mk8(a1, c1, b1, d1);                                                      \
  }

#define SUBSTEP(BUF, MC)                                                            \
  {                                                                                 \
    f32x16 sc0 = {}, sc1 = {};                                                      \
    const char* Kb = Ks + (BUF)*8192;                                               \
    __builtin_amdgcn_s_setprio(1);                                                  \
    _Pragma("unroll") for (int ds4 = 0; ds4 < 4; ++ds4) {                           \
      int part = (ds4 * 2 + h) ^ (qc & 7);                                          \
      short8 ak0 = *(const short8*)(Kb + qc * 128 + part * 16);                     \
      short8 ak1 = *(const short8*)(Kb + (32 + qc) * 128 + part * 16);              \
      sc0 = MFMA32(ak0, bq_[ds4], sc0);                                             \
      sc1 = MFMA32(ak1, bq_[ds4], sc1);                                             \
    }                                                                               \
    __builtin_amdgcn_s_setprio(0);                                                  \
    short8 pa00, pa01, pa10, pa11;                                                  \
    SM32(sc0, MC.x, pa00, pa01);                                                    \
    SM32(sc1, MC.y, pa10, pa11);                                                    \
    const char* Vb = Vts + (BUF)*8192;                                              \
    __builtin_amdgcn_s_setprio(1);                                                  \
    _Pragma("unroll") for (int nd = 0; nd < 2; ++nd) {                              \
      const char* vr = Vb + (nd * 32 + qc) * 128;                                   \
      short8 bv0 = *(const short8*)(vr + ((0 + h) ^ (qc & 7)) * 16);                \
      o_acc[nd] = MFMA32(pa00, bv0, o_acc[nd]);                                     \
      short8 bv1 = *(const short8*)(vr + ((2 + h) ^ (qc & 7)) * 16);                \
      o_acc[nd] = MFMA32(pa01, bv1, o_acc[nd]);                                     \
      short8 bv2 = *(const short8*)(vr + ((4 + h) ^ (qc & 7)) * 16);                \
      o_acc[nd] = MFMA32(pa10, bv2, o_acc[nd]);                                     \
      short8 bv3 = *(const short8*)(vr + ((6 + h) ^ (qc & 7)) * 16);                \
      o_acc[nd] = MFMA32(pa11, bv3, o_acc[nd]);                                     \
    }                                                                               \
    __builtin_amdgcn_s_setprio(0);                                                  \
    asm volatile("s_waitcnt lgkmcnt(0)" ::: "memory");                              \
    __builtin_amdgcn_s_barrier();                                                   \
  }

  STAGE(0, 0);
  uint2 mcur = *(const uint2*)(mrow + (long)myq * 64);
  uint2 mnxt = mcur;

  for (int kt2 = 0; kt2 < NT; kt2 += 2) {
    // ---- tile kt2 (buf 0) ----
    STAGE(kt2 + 1, 1);
    mnxt = *(const uint2*)(mrow + (long)myq * 64 + (kt2 + 1) * 2);
    asm volatile("s_waitcnt vmcnt(9)" ::: "memory");
    __builtin_amdgcn_s_barrier();
    SUBSTEP(0, mcur);
    // ---- tile kt2+1 (buf 1) ----
    if (kt2 + 2 < NT) {
      STAGE(kt2 + 2, 0);
      mcur = *(const uint2*)(mrow + (long)myq * 64 + (kt2 + 2) * 2);
      asm volatile("s_waitcnt vmcnt(9)" ::: "memory");
    } else {
      asm volatile("s_waitcnt vmcnt(0)" ::: "memory");
    }
    __builtin_amdgcn_s_barrier();
    SUBSTEP(1, mnxt);
  }
#undef SUBSTEP
#undef SM32
#undef STAGE

  // epilogue: full l per q (sum halves), redistribute 1/l to C-layout, store.
  lp += __shfl_xor(lp, 32);
#pragma unroll
  for (int r = 0; r < 16; ++r) {
    int ql = (r & 3) + 8 * (r >> 2) + 4 * h;
    float inv = 1.0f / __shfl(lp, ql);
    long qrow = q0 + ql;
    op[qrow * 64 + qc] = f2bf(o_acc[0][r] * inv);
    op[qrow * 64 + 32 + qc] = f2bf(o_acc[1][r] * inv);
  }
}

// ---------------------------------------------------------------- launch -----
extern "C" void kernel_launch(void* const* d_in, const int* in_sizes, int n_in,
                              void* d_out, int out_size, void* d_ws, size_t ws_size,
                              hipStream_t stream) {
  const float* q = (const float*)d_in[0];
  const float* k = (const float*)d_in[1];
  const float* v = (const float*)d_in[2];
  const int* mask = (const int*)d_in[3];
  const float* Wq = (const float*)d_in[4];
  const float* bq = (const float*)d_in[5];
  const float* Wk = (const float*)d_in[6];
  const float* bk = (const float*)d_in[7];
  const float* Wv = (const float*)d_in[8];
  const float* bv = (const float*)d_in[9];
  const float* Wo = (const float*)d_in[10];
  const float* bo = (const float*)d_in[11];
  const float* gamma = (const float*)d_in[12];
  const float* beta = (const float*)d_in[13];
  float* out = (float*)d_out;

  char* ws = (char*)d_ws;
  unsigned short* Wt = (unsigned short*)ws;                         // 8 MB
  unsigned* mbits = (unsigned*)(ws + 8u * 1024 * 1024);             // 1 MB
  unsigned short* lnq = (unsigned short*)(ws + 9u * 1024 * 1024);   // 8 MB
  unsigned short* lnk = lnq + 4194304;
  unsigned short* lnv = lnk + 4194304;
  unsigned short* qh = lnv + 4194304;
  unsigned short* kh = qh + 4194304;
  unsigned short* vtb = kh + 4194304;  // V^T written directly by QKV GEMM (z==2)
  unsigned short* Ob = lnq;            // alias: lnq dead after QKV GEMM

  wtrans_kernel<<<dim3(16, 16, 4), 256, 0, stream>>>(Wq, Wk, Wv, Wo, Wt);
  maskpack_kernel<<<1024, 256, 0, stream>>>(mask, mbits);
  ln_kernel<<<dim3(4096, 3), 256, 0, stream>>>(q, k, v, gamma, beta, lnq, lnk, lnv);
  gemm_kernel<128, 0><<<dim3(32, 8, 3), 256, 0, stream>>>(lnq, lnk, lnv, Wt, bq, bk, bv,
                                                          qh, vtb, nullptr);
  attn_kernel<<<dim3(32, 32), 128, 0, stream>>>(qh, kh, vtb, mbits, Ob);
  gemm_kernel<128, 1><<<dim3(32, 8, 1), 256, 0, stream>>>(Ob, Ob, Ob, Wt + 3 * 1048576,
                                                          bo, bo, bo, nullptr, nullptr, out);
}